// Round 11
// baseline (50.268 us; speedup 1.0000x reference)
//
#include <hip/hip_runtime.h>
#include <math.h>

#define BB 4
#define ND 256
#define NE 512
#define CC 256

#define K2E 2.8853900817779268f   // 2 * log2(e): exp2(K2E*x) = e^{2x}
#define LOG2E 1.4426950408889634f
#define LN2 0.6931471805599453f

typedef unsigned int u32;
typedef unsigned short u16;

__device__ __forceinline__ u16 f2bf(float f) {   // RTNE float->bf16
    u32 u = __builtin_bit_cast(u32, f);
    u += 0x7fffu + ((u >> 16) & 1u);
    return (u16)(u >> 16);
}
__device__ __forceinline__ float bflo(u32 u) { return __builtin_bit_cast(float, u << 16); }
__device__ __forceinline__ float bfhi(u32 u) { return __builtin_bit_cast(float, u & 0xffff0000u); }

// ---------------------------------------------------------------------------
// Projection GEMM + exp epilogue. IDENTICAL to R10 (measurement round).
// ---------------------------------------------------------------------------
__global__ __launch_bounds__(256) void proj_kernel(
    const float* __restrict__ xdec, const float* __restrict__ xenc,
    const float* __restrict__ w1,   const float* __restrict__ w2,
    u32* __restrict__ Et2, float* __restrict__ Dexp)
{
    __shared__ float Xs[16][36];
    __shared__ float Ws[16][68];
    __shared__ u32   T[32][33];    // [cp_local][e_local] transpose staging

    const int row0 = blockIdx.x * 32;
    const int col0 = blockIdx.y * 64;
    const bool is_enc = (row0 < BB * NE);

    const float* X = is_enc ? xenc : xdec;
    const float* W = is_enc ? w1   : w2;
    const int xrow0 = is_enc ? row0 : (row0 - BB * NE);

    const int tid = threadIdx.x;
    const int xr = tid >> 3, xk = (tid & 7) * 2;
    const int wc = tid >> 2, wk = (tid & 3) * 4;
    const int ty = tid >> 5;        // 0..7  (4 rows each)
    const int tx = tid & 31;        // 0..31 (2 cols each)

    float acc[4][2] = {};

    for (int k0 = 0; k0 < CC; k0 += 16) {
        float2 xv = *(const float2*)&X[(xrow0 + xr) * CC + k0 + xk];
        float4 wv = *(const float4*)&W[(col0 + wc) * CC + k0 + wk];
        __syncthreads();
        Xs[xk][xr] = xv.x; Xs[xk + 1][xr] = xv.y;
        Ws[wk][wc] = wv.x; Ws[wk + 1][wc] = wv.y;
        Ws[wk + 2][wc] = wv.z; Ws[wk + 3][wc] = wv.w;
        __syncthreads();
#pragma unroll
        for (int k = 0; k < 16; ++k) {
            float4 a = *(const float4*)&Xs[k][ty * 4];
            float2 b = *(const float2*)&Ws[k][tx * 2];
            acc[0][0] += a.x * b.x; acc[0][1] += a.x * b.y;
            acc[1][0] += a.y * b.x; acc[1][1] += a.y * b.y;
            acc[2][0] += a.z * b.x; acc[2][1] += a.z * b.y;
            acc[3][0] += a.w * b.x; acc[3][1] += a.w * b.y;
        }
    }

    float ex[4][2];
#pragma unroll
    for (int i = 0; i < 4; ++i)
#pragma unroll
        for (int j = 0; j < 2; ++j)
            ex[i][j] = __builtin_amdgcn_exp2f(
                K2E * fminf(fmaxf(acc[i][j], -9.f), 9.f));

    if (is_enc) {
#pragma unroll
        for (int i = 0; i < 4; ++i)
            T[tx][ty * 4 + i] = (u32)f2bf(ex[i][0]) | ((u32)f2bf(ex[i][1]) << 16);
        __syncthreads();
        const int b  = row0 >> 9;
        const int e0 = row0 & 511;
        const int el = tid & 31;
        const int c0 = tid >> 5;          // 0..7
#pragma unroll
        for (int i = 0; i < 4; ++i) {
            const int cpl = c0 + 8 * i;   // 0..31
            Et2[((size_t)b * (CC / 2) + (col0 >> 1) + cpl) * NE + e0 + el] = T[cpl][el];
        }
    } else {
#pragma unroll
        for (int i = 0; i < 4; ++i) {
            float2 o = make_float2(ex[i][0], ex[i][1]);
            *(float2*)&Dexp[(size_t)(xrow0 + ty * 4 + i) * CC + col0 + tx * 2] = o;
        }
    }
}

// ---------------------------------------------------------------------------
// Fused tanh-dot + log_softmax. IDENTICAL to R10 (measurement round).
// ---------------------------------------------------------------------------
__global__ __launch_bounds__(512) void attn_kernel(
    const u32* __restrict__ Et2, const float* __restrict__ Dexp,
    const float* __restrict__ v, float* __restrict__ out)
{
    __shared__ float prod[2][NE];

    const int blk = blockIdx.x;       // 0..511
    const int b   = blk >> 7;
    const int n0  = (blk & 127) * 2;
    const int tid = threadIdx.x;      // == e

    const float* __restrict__ D0 = Dexp + (size_t)(b * ND + n0) * CC;
    const float* __restrict__ D1 = D0 + CC;
    const u32* Ec = Et2 + (size_t)b * (CC / 2) * NE + tid;

    float a0 = 0.f, a1 = 0.f;
    u32 Eb0[8], Eb1[8];

#define PAIR(ACC, E0, E1, V0, V1, Dx0, Dx1) do {                             \
        const float _d0 = fmaf((E0), (Dx0), 1.0f);                           \
        const float _d1 = fmaf((E1), (Dx1), 1.0f);                           \
        const float _num = fmaf((V1), _d0, (V0) * _d1);                      \
        ACC = fmaf(_num, __builtin_amdgcn_rcpf(_d0 * _d1), ACC);             \
    } while (0)

#define LOADE(EB, CPB) do {                                                  \
        _Pragma("unroll")                                                    \
        for (int j = 0; j < 8; ++j)                                          \
            EB[j] = Ec[(size_t)((CPB) + j) * NE];                            \
    } while (0)

#define PROCESS(EB, CPB) do {                                                \
        _Pragma("unroll")                                                    \
        for (int j = 0; j < 8; ++j) {                                        \
            const int c = ((CPB) + j) * 2;                                   \
            const float vlo = v[c], vhi = v[c + 1];                          \
            const float e0f = bflo(EB[j]), e1f = bfhi(EB[j]);                \
            PAIR(a0, e0f, e1f, vlo, vhi, D0[c], D0[c + 1]);                  \
            PAIR(a1, e0f, e1f, vlo, vhi, D1[c], D1[c + 1]);                  \
        }                                                                    \
    } while (0)

    LOADE(Eb0, 0);
    for (int cp0 = 0; cp0 < CC / 2; cp0 += 16) {
        LOADE(Eb1, cp0 + 8);
        PROCESS(Eb0, cp0);
        if (cp0 + 16 < CC / 2) LOADE(Eb0, cp0 + 16);
        PROCESS(Eb1, cp0 + 8);
    }
#undef PROCESS
#undef LOADE
#undef PAIR

    prod[0][tid] = -2.0f * a0;
    prod[1][tid] = -2.0f * a1;
    __syncthreads();

    const int w    = tid >> 6;
    const int lane = tid & 63;
    if (w < 2) {
        float p[8];
#pragma unroll
        for (int i = 0; i < 8; ++i) p[i] = prod[w][lane + 64 * i];
        float m = p[0];
#pragma unroll
        for (int i = 1; i < 8; ++i) m = fmaxf(m, p[i]);
#pragma unroll
        for (int off = 1; off < 64; off <<= 1) m = fmaxf(m, __shfl_xor(m, off));
        float s = 0.f;
#pragma unroll
        for (int i = 0; i < 8; ++i) s += __builtin_amdgcn_exp2f((p[i] - m) * LOG2E);
#pragma unroll
        for (int off = 1; off < 64; off <<= 1) s += __shfl_xor(s, off);
        const float lse = m + __builtin_amdgcn_logf(s) * LN2;

        float* o = out + (size_t)(b * ND + n0 + w) * NE;
#pragma unroll
        for (int i = 0; i < 8; ++i) o[lane + 64 * i] = p[i] - lse;
    }
}

// ---------------------------------------------------------------------------
extern "C" void kernel_launch(void* const* d_in, const int* in_sizes, int n_in,
                              void* d_out, int out_size, void* d_ws, size_t ws_size,
                              hipStream_t stream) {
    const float* xdec = (const float*)d_in[0];   // (4,256,256)
    const float* xenc = (const float*)d_in[1];   // (4,512,256)
    const float* w1   = (const float*)d_in[2];   // (256,256)
    const float* w2   = (const float*)d_in[3];   // (256,256)
    const float* v    = (const float*)d_in[4];   // (1,256)
    float* out = (float*)d_out;                  // (4,256,512)

    char* ws = (char*)d_ws;
    u32*   Et2  = (u32*)ws;                      // [4][128][512] u32 = 1 MB (bf16 c-pairs)
    float* Dexp = (float*)(ws + (1u << 20));     // [1024][256] f32 = 1 MB

    dim3 gproj(96, 4);
    // MEASUREMENT ROUND: proj launched TWICE (idempotent, identical writes).
    // T11 - T10 = proj duration exactly (kernels byte-identical to R10).
    proj_kernel<<<gproj, 256, 0, stream>>>(xdec, xenc, w1, w2, Et2, Dexp);
    proj_kernel<<<gproj, 256, 0, stream>>>(xdec, xenc, w1, w2, Et2, Dexp);
    attn_kernel<<<(BB * ND) / 2, 512, 0, stream>>>(Et2, Dexp, v, out);
}

// Round 12
// 36.721 us; speedup vs baseline: 1.3689x; 1.3689x over previous
//
#include <hip/hip_runtime.h>
#include <math.h>

#define BB 4
#define ND 256
#define NE 512
#define CC 256

#define K2E 2.8853900817779268f   // 2 * log2(e): exp2(K2E*x) = e^{2x}
#define LOG2E 1.4426950408889634f
#define LN2 0.6931471805599453f

typedef unsigned int u32;
typedef unsigned short u16;

__device__ __forceinline__ u16 f2bf(float f) {   // RTNE float->bf16
    u32 u = __builtin_bit_cast(u32, f);
    u += 0x7fffu + ((u >> 16) & 1u);
    return (u16)(u >> 16);
}
__device__ __forceinline__ float bflo(u32 u) { return __builtin_bit_cast(float, u << 16); }
__device__ __forceinline__ float bfhi(u32 u) { return __builtin_bit_cast(float, u & 0xffff0000u); }

// ---------------------------------------------------------------------------
// Projection GEMM + exp epilogue.
//   enc: Et4[b][cq][e] = uint4{ cp0, cp1, cp2, cp3 } where cpq packs
//        bf16(E[8cq+2q][e]) | bf16(E[8cq+2q+1][e])<<16   (8 c per uint4)
//        -> attn reads 16B/lane, coalesced. Written via LDS transpose.
//   dec: Dexp[n][c] = exp2(K2E*clamp(x_dec@w2^T,+-9))  row-major f32
// Register ping-pong on the K-loop: next tile's loads issue before compute.
// ---------------------------------------------------------------------------
__global__ __launch_bounds__(256) void proj_kernel(
    const float* __restrict__ xdec, const float* __restrict__ xenc,
    const float* __restrict__ w1,   const float* __restrict__ w2,
    uint4* __restrict__ Et4, float* __restrict__ Dexp)
{
    __shared__ float Xs[16][36];
    __shared__ float Ws[16][68];
    __shared__ u32   T[32][33];    // [cp_local][e_local] transpose staging

    const int row0 = blockIdx.x * 32;
    const int col0 = blockIdx.y * 64;
    const bool is_enc = (row0 < BB * NE);

    const float* X = is_enc ? xenc : xdec;
    const float* W = is_enc ? w1   : w2;
    const int xrow0 = is_enc ? row0 : (row0 - BB * NE);

    const int tid = threadIdx.x;
    const int xr = tid >> 3, xk = (tid & 7) * 2;
    const int wc = tid >> 2, wk = (tid & 3) * 4;
    const int ty = tid >> 5;        // 0..7  (4 rows each)
    const int tx = tid & 31;        // 0..31 (2 cols each)

    float acc[4][2] = {};

    float2 xv = *(const float2*)&X[(xrow0 + xr) * CC + xk];
    float4 wv = *(const float4*)&W[(col0 + wc) * CC + wk];

    for (int k0 = 0; k0 < CC; k0 += 16) {
        __syncthreads();
        Xs[xk][xr] = xv.x; Xs[xk + 1][xr] = xv.y;
        Ws[wk][wc] = wv.x; Ws[wk + 1][wc] = wv.y;
        Ws[wk + 2][wc] = wv.z; Ws[wk + 3][wc] = wv.w;
        __syncthreads();
        if (k0 + 16 < CC) {   // prefetch next K-tile; consumed next iteration
            xv = *(const float2*)&X[(xrow0 + xr) * CC + k0 + 16 + xk];
            wv = *(const float4*)&W[(col0 + wc) * CC + k0 + 16 + wk];
        }
#pragma unroll
        for (int k = 0; k < 16; ++k) {
            float4 a = *(const float4*)&Xs[k][ty * 4];
            float2 b = *(const float2*)&Ws[k][tx * 2];
            acc[0][0] += a.x * b.x; acc[0][1] += a.x * b.y;
            acc[1][0] += a.y * b.x; acc[1][1] += a.y * b.y;
            acc[2][0] += a.z * b.x; acc[2][1] += a.z * b.y;
            acc[3][0] += a.w * b.x; acc[3][1] += a.w * b.y;
        }
    }

    float ex[4][2];
#pragma unroll
    for (int i = 0; i < 4; ++i)
#pragma unroll
        for (int j = 0; j < 2; ++j)
            ex[i][j] = __builtin_amdgcn_exp2f(
                K2E * fminf(fmaxf(acc[i][j], -9.f), 9.f));

    if (is_enc) {
        // stage packed c-pair words, transposed: T[cp_local][e_local]
#pragma unroll
        for (int i = 0; i < 4; ++i)
            T[tx][ty * 4 + i] = (u32)f2bf(ex[i][0]) | ((u32)f2bf(ex[i][1]) << 16);
        __syncthreads();
        const int b   = row0 >> 9;
        const int e0  = row0 & 511;
        const int eL  = tid & 31;        // e_local
        const int cqL = tid >> 5;        // 0..7
        const int cq0 = col0 >> 3;       // global cq base
        uint4 w4;
        w4.x = T[cqL * 4 + 0][eL];
        w4.y = T[cqL * 4 + 1][eL];
        w4.z = T[cqL * 4 + 2][eL];
        w4.w = T[cqL * 4 + 3][eL];
        Et4[((size_t)b * 32 + cq0 + cqL) * 512 + e0 + eL] = w4;
    } else {
#pragma unroll
        for (int i = 0; i < 4; ++i) {
            float2 o = make_float2(ex[i][0], ex[i][1]);
            *(float2*)&Dexp[(size_t)(xrow0 + ty * 4 + i) * CC + col0 + tx * 2] = o;
        }
    }
}

// ---------------------------------------------------------------------------
// Fused tanh-dot + log_softmax, paired division, 16B-packed E loads.
//   p'[n,e] = -2 * sum_c v_c / (1 + E*D)    (sum(v) shift cancels)
//   v0/d0 + v1/d1 = (v0*d1 + v1*d0) / (d0*d1),  d = fma(E, D, 1)
// 512 thr (tid = e), 2 decoder rows/block, 512 blocks (4 waves/SIMD).
// Per thread: 32 dwordx4 E loads (was 128 dwords); D/v via uniform float4.
// ---------------------------------------------------------------------------
__global__ __launch_bounds__(512) void attn_kernel(
    const uint4* __restrict__ Et4, const float* __restrict__ Dexp,
    const float* __restrict__ v, float* __restrict__ out)
{
    __shared__ float prod[2][NE];

    const int blk = blockIdx.x;       // 0..511
    const int b   = blk >> 7;
    const int n0  = (blk & 127) * 2;
    const int tid = threadIdx.x;      // == e

    const float* __restrict__ D0 = Dexp + (size_t)(b * ND + n0) * CC;
    const float* __restrict__ D1 = D0 + CC;
    const uint4* Ec = Et4 + (size_t)b * 32 * 512 + tid;

    float a0 = 0.f, a1 = 0.f;

#define PAIR(ACC, E0, E1, V0, V1, Dx0, Dx1) do {                             \
        const float _d0 = fmaf((E0), (Dx0), 1.0f);                           \
        const float _d1 = fmaf((E1), (Dx1), 1.0f);                           \
        const float _num = fmaf((V1), _d0, (V0) * _d1);                      \
        ACC = fmaf(_num, __builtin_amdgcn_rcpf(_d0 * _d1), ACC);             \
    } while (0)

#define PROC(E4, CQ) do {                                                    \
        const int c8 = (CQ) * 8;                                             \
        const float4 vA  = *(const float4*)&v [c8];                          \
        const float4 vB  = *(const float4*)&v [c8 + 4];                      \
        const float4 dA0 = *(const float4*)&D0[c8];                          \
        const float4 dB0 = *(const float4*)&D0[c8 + 4];                      \
        const float4 dA1 = *(const float4*)&D1[c8];                          \
        const float4 dB1 = *(const float4*)&D1[c8 + 4];                      \
        PAIR(a0, bflo(E4.x), bfhi(E4.x), vA.x, vA.y, dA0.x, dA0.y);          \
        PAIR(a1, bflo(E4.x), bfhi(E4.x), vA.x, vA.y, dA1.x, dA1.y);          \
        PAIR(a0, bflo(E4.y), bfhi(E4.y), vA.z, vA.w, dA0.z, dA0.w);          \
        PAIR(a1, bflo(E4.y), bfhi(E4.y), vA.z, vA.w, dA1.z, dA1.w);          \
        PAIR(a0, bflo(E4.z), bfhi(E4.z), vB.x, vB.y, dB0.x, dB0.y);          \
        PAIR(a1, bflo(E4.z), bfhi(E4.z), vB.x, vB.y, dB1.x, dB1.y);          \
        PAIR(a0, bflo(E4.w), bfhi(E4.w), vB.z, vB.w, dB0.z, dB0.w);          \
        PAIR(a1, bflo(E4.w), bfhi(E4.w), vB.z, vB.w, dB1.z, dB1.w);          \
    } while (0)

    uint4 e4a = Ec[0], e4b;
    for (int cq = 0; cq < 32; cq += 2) {
        e4b = Ec[(size_t)(cq + 1) * 512];
        PROC(e4a, cq);
        if (cq + 2 < 32) e4a = Ec[(size_t)(cq + 2) * 512];
        PROC(e4b, cq + 1);
    }
#undef PROC
#undef PAIR

    prod[0][tid] = -2.0f * a0;
    prod[1][tid] = -2.0f * a1;
    __syncthreads();

    // log_softmax: wave w (w<2) handles decoder row n0+w
    const int w    = tid >> 6;
    const int lane = tid & 63;
    if (w < 2) {
        float p[8];
#pragma unroll
        for (int i = 0; i < 8; ++i) p[i] = prod[w][lane + 64 * i];
        float m = p[0];
#pragma unroll
        for (int i = 1; i < 8; ++i) m = fmaxf(m, p[i]);
#pragma unroll
        for (int off = 1; off < 64; off <<= 1) m = fmaxf(m, __shfl_xor(m, off));
        float s = 0.f;
#pragma unroll
        for (int i = 0; i < 8; ++i) s += __builtin_amdgcn_exp2f((p[i] - m) * LOG2E);
#pragma unroll
        for (int off = 1; off < 64; off <<= 1) s += __shfl_xor(s, off);
        const float lse = m + __builtin_amdgcn_logf(s) * LN2;

        float* o = out + (size_t)(b * ND + n0 + w) * NE;
#pragma unroll
        for (int i = 0; i < 8; ++i) o[lane + 64 * i] = p[i] - lse;
    }
}

// ---------------------------------------------------------------------------
extern "C" void kernel_launch(void* const* d_in, const int* in_sizes, int n_in,
                              void* d_out, int out_size, void* d_ws, size_t ws_size,
                              hipStream_t stream) {
    const float* xdec = (const float*)d_in[0];   // (4,256,256)
    const float* xenc = (const float*)d_in[1];   // (4,512,256)
    const float* w1   = (const float*)d_in[2];   // (256,256)
    const float* w2   = (const float*)d_in[3];   // (256,256)
    const float* v    = (const float*)d_in[4];   // (1,256)
    float* out = (float*)d_out;                  // (4,256,512)

    char* ws = (char*)d_ws;
    uint4* Et4  = (uint4*)ws;                    // [4][32][512] uint4 = 1 MB
    float* Dexp = (float*)(ws + (1u << 20));     // [1024][256] f32 = 1 MB

    dim3 gproj(96, 4);
    proj_kernel<<<gproj, 256, 0, stream>>>(xdec, xenc, w1, w2, Et4, Dexp);
    attn_kernel<<<(BB * ND) / 2, 512, 0, stream>>>(Et4, Dexp, v, out);
}